// Round 1
// baseline (2137.564 us; speedup 1.0000x reference)
//
#include <hip/hip_runtime.h>
#include <math.h>

// ============================================================================
// ConcatenatedIrrepsTensorProduct — fused fp32 implementation, round 1.
//
// Per block: 64 events, 512 threads. All stages fused:
//   MLP:  h1 = cst*silu(scalars@Wm1/8); h2 = cst*silu(h1@Wm2/8); wts = h2@Wm3/8
//   TP :  mid0=s0@w0, p2=s0@w2, mid1=t1@w1, mid3k=s1k@w3   (all K=64,N=32)
//   out:  o0  = (concat(mid0*PW*y0, mid1*PW/sqrt3) * wts[0:64])  @ C0
//         o1k = (concat(p2*PW*y1k,  mid3k*PW*y0) * wts[64:128]) @ C1
//   where C0 = Wl0@Wf0/(8*sqrt(32)), C1 = Wl1@Wf1/(8*sqrt(32))  (prep kernel)
//
// LDS: sBuf 64x65 fp32 (A-tile, stride 65 = bank-conflict-free),
//      sWB 64x32 fp32 (staged weight block), sWTS 64x128 fp32 (gate weights).
// Total 57.6 KB -> 2 blocks/CU, 16 waves/CU.
// ============================================================================

#define TPB 512
#define ET  64

// ---------------------------------------------------------------------------
// prep: SILU_CST integral (fp64 trapz identical to reference's np.trapz)
// ---------------------------------------------------------------------------
__global__ void zero_cst_kernel(double* cst) {
  if (threadIdx.x == 0) cst[0] = 0.0;
}

__global__ void cst_accum_kernel(double* cst) {
  __shared__ double red[256];
  double sum = 0.0;
  for (long i = (long)blockIdx.x * 256 + threadIdx.x; i <= 200000; i += 64L * 256) {
    double z = -12.0 + (double)i * (24.0 / 200000.0);
    double s = z / (1.0 + exp(-z));                       // silu(z)
    double phi = exp(-0.5 * z * z) * 0.3989422804014327;  // 1/sqrt(2*pi)
    double f = s * s * phi;
    if (i == 0 || i == 200000) f *= 0.5;                  // trapz end weights
    sum += f;
  }
  red[threadIdx.x] = sum;
  __syncthreads();
  for (int off = 128; off > 0; off >>= 1) {
    if (threadIdx.x < (unsigned)off) red[threadIdx.x] += red[threadIdx.x + off];
    __syncthreads();
  }
  if (threadIdx.x == 0) atomicAdd(cst, red[0]);
}

// ---------------------------------------------------------------------------
// prep: C0 = Wl0@Wf0 * 1/(8*sqrt(32)), C1 = Wl1@Wf1 * same   (64x32 each)
// ---------------------------------------------------------------------------
__global__ void prep_C_kernel(const float* __restrict__ Wl0, const float* __restrict__ Wf0,
                              const float* __restrict__ Wl1, const float* __restrict__ Wf1,
                              float* __restrict__ C0, float* __restrict__ C1) {
  const float* Wl = blockIdx.x ? Wl1 : Wl0;
  const float* Wf = blockIdx.x ? Wf1 : Wf0;
  float* C = blockIdx.x ? C1 : C0;
  for (int i = threadIdx.x; i < 64 * 32; i += 256) {
    int u = i >> 5, w = i & 31;
    float acc = 0.f;
#pragma unroll
    for (int v = 0; v < 32; ++v) acc = fmaf(Wl[u * 32 + v], Wf[v * 32 + w], acc);
    C[i] = acc * 0.022097086912079612f;  // 1/(sqrt(64)*sqrt(32))
  }
}

// ---------------------------------------------------------------------------
// fused main kernel
// ---------------------------------------------------------------------------
__device__ __forceinline__ void stage32(const float* __restrict__ g, int ncols, int col0,
                                        float* __restrict__ sWB, int t) {
  // copy a 64 x 32 column block of a row-major [64][ncols] matrix into sWB[c][32]
#pragma unroll
  for (int r = 0; r < 4; ++r) {
    int i = t + r * TPB;          // 0..2047
    int c = i >> 5, j = i & 31;
    sWB[i] = g[c * ncols + col0 + j];
  }
}

__device__ __forceinline__ void gemm32(const float* __restrict__ A, const float* __restrict__ B,
                                       int ev, int cg, float acc[4]) {
  // out[ev][4cg..4cg+3] = sum_c A[ev][c] * B[c][4cg..4cg+3];  A stride 65, B stride 32
  const float* ar = A + ev * 65;
  const float* br = B + 4 * cg;
  float a0 = 0.f, a1 = 0.f, a2 = 0.f, a3 = 0.f;
#pragma unroll
  for (int c = 0; c < 64; ++c) {
    float a = ar[c];
    float4 b = *(const float4*)(br + c * 32);
    a0 = fmaf(a, b.x, a0);
    a1 = fmaf(a, b.y, a1);
    a2 = fmaf(a, b.z, a2);
    a3 = fmaf(a, b.w, a3);
  }
  acc[0] = a0; acc[1] = a1; acc[2] = a2; acc[3] = a3;
}

__global__ __launch_bounds__(TPB) void fused_tp(
    const float* __restrict__ x1a, const float* __restrict__ x1b,
    const float* __restrict__ x2, const float* __restrict__ scalars,
    const float* __restrict__ w0, const float* __restrict__ w1,
    const float* __restrict__ w2, const float* __restrict__ w3,
    const float* __restrict__ Wm1, const float* __restrict__ Wm2,
    const float* __restrict__ Wm3, const float* __restrict__ C0,
    const float* __restrict__ C1, const double* __restrict__ cstp,
    float* __restrict__ out) {
  __shared__ float sBuf[ET * 65];    // 16640 B  A-tile
  __shared__ float sWB[64 * 32];     //  8192 B  staged weight block
  __shared__ float sWTS[ET * 128];   // 32768 B  gate weights

  const int t = threadIdx.x;
  const long e0 = (long)blockIdx.x * ET;
  const int ev = t >> 3;   // 0..63 event within tile (gemm mapping)
  const int cg = t & 7;    // 0..7 column group
  const long eg = e0 + ev; // this thread's event

  const float cst = (float)(1.0 / sqrt(cstp[0] * (24.0 / 200000.0)));  // SILU_CST

  float acc[4];
  float hreg[8];

  // ---- load scalars tile into sBuf
  for (int i = t; i < ET * 64; i += TPB) {
    int e = i >> 6, c = i & 63;
    sBuf[e * 65 + c] = scalars[(e0 + e) * 64 + c];
  }

  // ---- h1 = cst * silu(scalars @ Wm1 / 8), two 32-col passes
  stage32(Wm1, 64, 0, sWB, t);
  __syncthreads();
  gemm32(sBuf, sWB, ev, cg, acc);
#pragma unroll
  for (int j = 0; j < 4; ++j) { float x = acc[j] * 0.125f; hreg[j] = cst * x / (1.f + expf(-x)); }
  __syncthreads();
  stage32(Wm1, 64, 32, sWB, t);
  __syncthreads();
  gemm32(sBuf, sWB, ev, cg, acc);
#pragma unroll
  for (int j = 0; j < 4; ++j) { float x = acc[j] * 0.125f; hreg[4 + j] = cst * x / (1.f + expf(-x)); }
  __syncthreads();  // everyone done reading sBuf(scalars) & sWB

  // ---- write h1 into sBuf; stage Wm2
#pragma unroll
  for (int j = 0; j < 4; ++j) {
    sBuf[ev * 65 + 4 * cg + j]      = hreg[j];
    sBuf[ev * 65 + 32 + 4 * cg + j] = hreg[4 + j];
  }
  stage32(Wm2, 64, 0, sWB, t);
  __syncthreads();

  // ---- h2 = cst * silu(h1 @ Wm2 / 8)
  gemm32(sBuf, sWB, ev, cg, acc);
#pragma unroll
  for (int j = 0; j < 4; ++j) { float x = acc[j] * 0.125f; hreg[j] = cst * x / (1.f + expf(-x)); }
  __syncthreads();
  stage32(Wm2, 64, 32, sWB, t);
  __syncthreads();
  gemm32(sBuf, sWB, ev, cg, acc);
#pragma unroll
  for (int j = 0; j < 4; ++j) { float x = acc[j] * 0.125f; hreg[4 + j] = cst * x / (1.f + expf(-x)); }
  __syncthreads();

  // ---- write h2 into sBuf
#pragma unroll
  for (int j = 0; j < 4; ++j) {
    sBuf[ev * 65 + 4 * cg + j]      = hreg[j];
    sBuf[ev * 65 + 32 + 4 * cg + j] = hreg[4 + j];
  }

  // ---- wts = h2 @ Wm3 / 8  (four 32-col passes) -> sWTS
#pragma unroll 1
  for (int wc = 0; wc < 4; ++wc) {
    stage32(Wm3, 128, wc * 32, sWB, t);
    __syncthreads();
    gemm32(sBuf, sWB, ev, cg, acc);
#pragma unroll
    for (int j = 0; j < 4; ++j) sWTS[ev * 128 + wc * 32 + 4 * cg + j] = acc[j] * 0.125f;
    __syncthreads();
  }

  // ---- per-event x2 values
  float y0v  = x2[eg * 4 + 0];
  float y1v0 = x2[eg * 4 + 1];
  float y1v1 = x2[eg * 4 + 2];
  float y1v2 = x2[eg * 4 + 3];

  // ---- s0 tile; mid0 = s0 @ w0 (raw), p2 = s0 @ w2 (raw)
  for (int i = t; i < ET * 64; i += TPB) {
    int e = i >> 6, u = i & 63;
    const float* xr = (u < 32 ? x1a : x1b) + (e0 + e) * 128;
    sBuf[e * 65 + u] = xr[u & 31];
  }
  stage32(w0, 32, 0, sWB, t);
  __syncthreads();
  float r_m0[4];
  gemm32(sBuf, sWB, ev, cg, r_m0);
  __syncthreads();
  stage32(w2, 32, 0, sWB, t);
  __syncthreads();
  float r_p2[4];
  gemm32(sBuf, sWB, ev, cg, r_p2);
  __syncthreads();

  // ---- t1 tile; mid1 = t1 @ w1 (raw)
  for (int i = t; i < ET * 64; i += TPB) {
    int e = i >> 6, u = i & 63;
    const float* xr = (u < 32 ? x1a : x1b) + (e0 + e) * 128;
    int ub = 32 + (u & 31) * 3;
    const float* yr = x2 + (e0 + e) * 4;
    sBuf[e * 65 + u] = xr[ub] * yr[1] + xr[ub + 1] * yr[2] + xr[ub + 2] * yr[3];
  }
  stage32(w1, 32, 0, sWB, t);
  __syncthreads();
  float r_m1[4];
  gemm32(sBuf, sWB, ev, cg, r_m1);
  __syncthreads();

  // ---- mid3k = s1k @ w3 (raw), k = 0..2
  float r_m3[3][4];
#pragma unroll 1
  for (int k = 0; k < 3; ++k) {
    for (int i = t; i < ET * 64; i += TPB) {
      int e = i >> 6, u = i & 63;
      const float* xr = (u < 32 ? x1a : x1b) + (e0 + e) * 128;
      sBuf[e * 65 + u] = xr[32 + (u & 31) * 3 + k];
    }
    if (k == 0) stage32(w3, 32, 0, sWB, t);
    __syncthreads();
    gemm32(sBuf, sWB, ev, cg, r_m3[k]);
    __syncthreads();
  }

  // ---- o0: M0 = concat(PW*y0*mid0, PW/sqrt3*mid1) * wts[0:64];  out[0:32] = M0 @ C0
  const float pw   = 0.125f;
  const float pws3 = 0.125f * 0.57735026918962576f;
#pragma unroll
  for (int j = 0; j < 4; ++j) {
    sBuf[ev * 65 + 4 * cg + j]      = pw * y0v * r_m0[j] * sWTS[ev * 128 + 4 * cg + j];
    sBuf[ev * 65 + 32 + 4 * cg + j] = pws3 *      r_m1[j] * sWTS[ev * 128 + 32 + 4 * cg + j];
  }
  stage32(C0, 32, 0, sWB, t);
  __syncthreads();
  gemm32(sBuf, sWB, ev, cg, acc);
  *(float4*)(out + eg * 128 + 4 * cg) = make_float4(acc[0], acc[1], acc[2], acc[3]);
  __syncthreads();

  // ---- o1k: M1k = concat(PW*y1k*p2, PW*y0*mid3k) * wts[64:128]; out[32+3w+k] = M1k @ C1
#pragma unroll 1
  for (int k = 0; k < 3; ++k) {
    float y1k = (k == 0) ? y1v0 : (k == 1) ? y1v1 : y1v2;
#pragma unroll
    for (int j = 0; j < 4; ++j) {
      sBuf[ev * 65 + 4 * cg + j]      = pw * y1k * r_p2[j]    * sWTS[ev * 128 + 64 + 4 * cg + j];
      sBuf[ev * 65 + 32 + 4 * cg + j] = pw * y0v * r_m3[k][j] * sWTS[ev * 128 + 96 + 4 * cg + j];
    }
    if (k == 0) stage32(C1, 32, 0, sWB, t);
    __syncthreads();
    gemm32(sBuf, sWB, ev, cg, acc);
#pragma unroll
    for (int j = 0; j < 4; ++j) out[eg * 128 + 32 + 3 * (4 * cg + j) + k] = acc[j];
    __syncthreads();
  }
}

// ---------------------------------------------------------------------------
extern "C" void kernel_launch(void* const* d_in, const int* in_sizes, int n_in,
                              void* d_out, int out_size, void* d_ws, size_t ws_size,
                              hipStream_t stream) {
  const float* x1a     = (const float*)d_in[0];
  const float* x1b     = (const float*)d_in[1];
  const float* x2      = (const float*)d_in[2];
  const float* scalars = (const float*)d_in[3];
  const float* w0      = (const float*)d_in[4];
  const float* w1      = (const float*)d_in[5];
  const float* w2      = (const float*)d_in[6];
  const float* w3      = (const float*)d_in[7];
  const float* Wl0     = (const float*)d_in[8];
  const float* Wl1     = (const float*)d_in[9];
  const float* Wm1     = (const float*)d_in[10];
  const float* Wm2     = (const float*)d_in[11];
  const float* Wm3     = (const float*)d_in[12];
  const float* Wf0     = (const float*)d_in[13];
  const float* Wf1     = (const float*)d_in[14];
  float* out = (float*)d_out;

  double* cst = (double*)d_ws;
  float* C0 = (float*)d_ws + 64;   // 64 floats of headroom past the double
  float* C1 = C0 + 64 * 32;

  const int E = in_sizes[0] / 128;      // 200000
  const int nblocks = E / ET;           // 3125

  zero_cst_kernel<<<1, 64, 0, stream>>>(cst);
  cst_accum_kernel<<<64, 256, 0, stream>>>(cst);
  prep_C_kernel<<<2, 256, 0, stream>>>(Wl0, Wf0, Wl1, Wf1, C0, C1);
  fused_tp<<<nblocks, TPB, 0, stream>>>(x1a, x1b, x2, scalars, w0, w1, w2, w3,
                                        Wm1, Wm2, Wm3, C0, C1, cst, out);
}

// Round 2
// 486.224 us; speedup vs baseline: 4.3963x; 4.3963x over previous
//
#include <hip/hip_runtime.h>
#include <math.h>

// ============================================================================
// ConcatenatedIrrepsTensorProduct — fused fp32, round 2.
//
// Changes vs round 1 (which was LDS-issue bound: VALUBusy 9%, 1854 us):
//  - 2 events x 4 cols per thread; A-tile read as aligned float4 (stride 68).
//    Per 32 FMAs: 6 broadcast b128 LDS reads (was 8 b32 + 8 b128 per 32).
//  - gate weights (wts) kept in registers (each thread computes exactly the
//    columns it later consumes) -> sWTS LDS buffer (32 KB) eliminated.
//  - o0/o1 accumulated in regs, written ONCE as 4 contiguous float4/event
//    (round 1's scattered 4B stores caused 3.45 GB WRITE_SIZE vs 102 MB ideal).
//  - double-staged B (two 8 KB slots) halves barrier count.
// LDS: sA 64x68 f32 (17.4 KB) + 2x B slot (16 KB) + sY (1 KB) = 34.8 KB
//      -> 4 blocks/CU at __launch_bounds__(256,4).
// ============================================================================

#define TPB 256
#define ET  64
#define SAS 68   // sA row stride in floats: rows 16B-aligned, b128 conflict-free

#define FMA4(acc, s, b)                                         \
  acc.x = fmaf((s), (b).x, acc.x); acc.y = fmaf((s), (b).y, acc.y); \
  acc.z = fmaf((s), (b).z, acc.z); acc.w = fmaf((s), (b).w, acc.w)

// ---------------------------------------------------------------------------
// prep: SILU_CST integral (fp64 trapz identical to reference's np.trapz)
// ---------------------------------------------------------------------------
__global__ void zero_cst_kernel(double* cst) {
  if (threadIdx.x == 0) cst[0] = 0.0;
}

__global__ void cst_accum_kernel(double* cst) {
  __shared__ double red[256];
  double sum = 0.0;
  for (long i = (long)blockIdx.x * 256 + threadIdx.x; i <= 200000; i += 64L * 256) {
    double z = -12.0 + (double)i * (24.0 / 200000.0);
    double s = z / (1.0 + exp(-z));
    double phi = exp(-0.5 * z * z) * 0.3989422804014327;
    double f = s * s * phi;
    if (i == 0 || i == 200000) f *= 0.5;
    sum += f;
  }
  red[threadIdx.x] = sum;
  __syncthreads();
  for (int off = 128; off > 0; off >>= 1) {
    if (threadIdx.x < (unsigned)off) red[threadIdx.x] += red[threadIdx.x + off];
    __syncthreads();
  }
  if (threadIdx.x == 0) atomicAdd(cst, red[0]);
}

// ---------------------------------------------------------------------------
// prep: C0 = Wl0@Wf0 /(8*sqrt32), C1 = Wl1@Wf1 /(8*sqrt32)   (64x32 each)
// ---------------------------------------------------------------------------
__global__ void prep_C_kernel(const float* __restrict__ Wl0, const float* __restrict__ Wf0,
                              const float* __restrict__ Wl1, const float* __restrict__ Wf1,
                              float* __restrict__ C0, float* __restrict__ C1) {
  const float* Wl = blockIdx.x ? Wl1 : Wl0;
  const float* Wf = blockIdx.x ? Wf1 : Wf0;
  float* C = blockIdx.x ? C1 : C0;
  for (int i = threadIdx.x; i < 64 * 32; i += 256) {
    int u = i >> 5, w = i & 31;
    float acc = 0.f;
#pragma unroll
    for (int v = 0; v < 32; ++v) acc = fmaf(Wl[u * 32 + v], Wf[v * 32 + w], acc);
    C[i] = acc * 0.022097086912079612f;  // 1/(sqrt(64)*sqrt(32))
  }
}

// ---------------------------------------------------------------------------
// device helpers
// ---------------------------------------------------------------------------
__device__ __forceinline__ void stageB(const float* __restrict__ g, int ncols, int col0,
                                       float* __restrict__ sB, int t) {
  // copy 64 x 32 column block of row-major [64][ncols] into sB[c*32+j]
#pragma unroll
  for (int r = 0; r < 2; ++r) {
    int i = (r * TPB + t) * 4;     // 0..2044 step 4
    int c = i >> 5, j = i & 31;
    *(float4*)(sB + i) = *(const float4*)(g + c * ncols + col0 + j);
  }
}

// out[e][4cg..4cg+3] for e in {e0l, e1l}: A stride SAS, B stride 32
__device__ __forceinline__ void gemm2(const float* __restrict__ sA,
                                      const float* __restrict__ sB,
                                      int e0l, int e1l, int cg,
                                      float4& out0, float4& out1) {
  float4 acc0 = make_float4(0.f, 0.f, 0.f, 0.f);
  float4 acc1 = make_float4(0.f, 0.f, 0.f, 0.f);
  const float* a0p = sA + e0l * SAS;
  const float* a1p = sA + e1l * SAS;
  const float* bp  = sB + 4 * cg;
#pragma unroll 4
  for (int c4 = 0; c4 < 16; ++c4) {
    float4 a0 = *(const float4*)(a0p + 4 * c4);
    float4 a1 = *(const float4*)(a1p + 4 * c4);
    const float* bb = bp + c4 * 128;
    float4 b0 = *(const float4*)(bb);
    float4 b1 = *(const float4*)(bb + 32);
    float4 b2 = *(const float4*)(bb + 64);
    float4 b3 = *(const float4*)(bb + 96);
    FMA4(acc0, a0.x, b0); FMA4(acc1, a1.x, b0);
    FMA4(acc0, a0.y, b1); FMA4(acc1, a1.y, b1);
    FMA4(acc0, a0.z, b2); FMA4(acc1, a1.z, b2);
    FMA4(acc0, a0.w, b3); FMA4(acc1, a1.w, b3);
  }
  out0 = acc0;
  out1 = acc1;
}

__device__ __forceinline__ float silu1(float x, float cst) {
  x *= 0.125f;
  return cst * x / (1.f + __expf(-x));
}

__device__ __forceinline__ float4 siluq(float4 v, float cst) {
  return make_float4(silu1(v.x, cst), silu1(v.y, cst), silu1(v.z, cst), silu1(v.w, cst));
}

__device__ __forceinline__ float4 muls(float4 a, float s) {
  return make_float4(a.x * s, a.y * s, a.z * s, a.w * s);
}

__device__ __forceinline__ float4 cmul(float4 a, float4 b, float s) {
  return make_float4(s * a.x * b.x, s * a.y * b.y, s * a.z * b.z, s * a.w * b.w);
}

// ---------------------------------------------------------------------------
// fused main kernel
// ---------------------------------------------------------------------------
__global__ __launch_bounds__(TPB, 4) void fused_tp(
    const float* __restrict__ x1a, const float* __restrict__ x1b,
    const float* __restrict__ x2, const float* __restrict__ scalars,
    const float* __restrict__ w0, const float* __restrict__ w1,
    const float* __restrict__ w2, const float* __restrict__ w3,
    const float* __restrict__ Wm1, const float* __restrict__ Wm2,
    const float* __restrict__ Wm3, const float* __restrict__ C0,
    const float* __restrict__ C1, const double* __restrict__ cstp,
    float* __restrict__ out) {
  __shared__ float sA[ET * SAS];   // 17408 B
  __shared__ float sB0[64 * 32];   //  8192 B
  __shared__ float sB1[64 * 32];   //  8192 B
  __shared__ float sY[ET * 4];     //  1024 B

  const int t  = threadIdx.x;
  const int cg = t & 7;            // 0..7  column group (4 cols)
  const int eh = t >> 3;           // 0..31 first event; second is eh+32
  const long e0 = (long)blockIdx.x * ET;
  const float cst = (float)(1.0 / sqrt(cstp[0] * (24.0 / 200000.0)));

  const float pw   = 0.125f;
  const float pws3 = 0.125f * 0.57735026918962576f;

  // ---- y tile + scalars tile + Wm1 staging
  if (t < ET) *(float4*)(sY + 4 * t) = *(const float4*)(x2 + (e0 + t) * 4);
#pragma unroll
  for (int r = 0; r < 4; ++r) {
    int i = r * TPB + t; int e = i >> 4; int j4 = (i & 15) << 2;
    *(float4*)(sA + e * SAS + j4) = *(const float4*)(scalars + (e0 + e) * 64 + j4);
  }
  stageB(Wm1, 64, 0, sB0, t);
  stageB(Wm1, 64, 32, sB1, t);
  __syncthreads();

  // ---- h1 = cst * silu(scalars @ Wm1 / 8)
  float4 h0a, h0b, h1a, h1b;
  {
    float4 r0, r1;
    gemm2(sA, sB0, eh, eh + 32, cg, r0, r1);
    h0a = siluq(r0, cst); h1a = siluq(r1, cst);
    gemm2(sA, sB1, eh, eh + 32, cg, r0, r1);
    h0b = siluq(r0, cst); h1b = siluq(r1, cst);
  }
  __syncthreads();

  // ---- write h1 -> sA; stage Wm2
  *(float4*)(sA + eh * SAS + 4 * cg)        = h0a;
  *(float4*)(sA + eh * SAS + 32 + 4 * cg)   = h0b;
  *(float4*)(sA + (eh + 32) * SAS + 4 * cg)      = h1a;
  *(float4*)(sA + (eh + 32) * SAS + 32 + 4 * cg) = h1b;
  stageB(Wm2, 64, 0, sB0, t);
  stageB(Wm2, 64, 32, sB1, t);
  __syncthreads();

  // ---- h2 = cst * silu(h1 @ Wm2 / 8)
  {
    float4 r0, r1;
    gemm2(sA, sB0, eh, eh + 32, cg, r0, r1);
    h0a = siluq(r0, cst); h1a = siluq(r1, cst);
    gemm2(sA, sB1, eh, eh + 32, cg, r0, r1);
    h0b = siluq(r0, cst); h1b = siluq(r1, cst);
  }
  __syncthreads();

  // ---- write h2 -> sA; stage Wm3 blocks 0,1
  *(float4*)(sA + eh * SAS + 4 * cg)        = h0a;
  *(float4*)(sA + eh * SAS + 32 + 4 * cg)   = h0b;
  *(float4*)(sA + (eh + 32) * SAS + 4 * cg)      = h1a;
  *(float4*)(sA + (eh + 32) * SAS + 32 + 4 * cg) = h1b;
  stageB(Wm3, 128, 0, sB0, t);
  stageB(Wm3, 128, 32, sB1, t);
  __syncthreads();

  // ---- wts = h2 @ Wm3 / 8 -> registers wq[ei][block]
  float4 wq[2][4];
  {
    float4 r0, r1;
    gemm2(sA, sB0, eh, eh + 32, cg, r0, r1);
    wq[0][0] = muls(r0, 0.125f); wq[1][0] = muls(r1, 0.125f);
    gemm2(sA, sB1, eh, eh + 32, cg, r0, r1);
    wq[0][1] = muls(r0, 0.125f); wq[1][1] = muls(r1, 0.125f);
  }
  __syncthreads();
  stageB(Wm3, 128, 64, sB0, t);
  stageB(Wm3, 128, 96, sB1, t);
  __syncthreads();
  {
    float4 r0, r1;
    gemm2(sA, sB0, eh, eh + 32, cg, r0, r1);
    wq[0][2] = muls(r0, 0.125f); wq[1][2] = muls(r1, 0.125f);
    gemm2(sA, sB1, eh, eh + 32, cg, r0, r1);
    wq[0][3] = muls(r0, 0.125f); wq[1][3] = muls(r1, 0.125f);
  }
  __syncthreads();

  // ---- s0 tile; mid0 = s0 @ w0, p2 = s0 @ w2
#pragma unroll
  for (int r = 0; r < 4; ++r) {
    int i = r * TPB + t; int e = i >> 4; int j4 = (i & 15) << 2;
    const float* src = (j4 < 32) ? (x1a + (e0 + e) * 128 + j4)
                                 : (x1b + (e0 + e) * 128 + j4 - 32);
    *(float4*)(sA + e * SAS + j4) = *(const float4*)src;
  }
  stageB(w0, 32, 0, sB0, t);
  stageB(w2, 32, 0, sB1, t);
  __syncthreads();
  float4 m0q[2], p2q[2];
  gemm2(sA, sB0, eh, eh + 32, cg, m0q[0], m0q[1]);
  gemm2(sA, sB1, eh, eh + 32, cg, p2q[0], p2q[1]);
  __syncthreads();

  // ---- t1 tile; mid1 = t1 @ w1  (w3 staged alongside for later)
#pragma unroll 2
  for (int r = 0; r < 16; ++r) {
    int i = r * TPB + t; int e = i >> 6; int u = i & 63;
    const float* xr = ((u < 32) ? x1a : x1b) + (e0 + e) * 128 + 32 + 3 * (u & 31);
    const float* yr = sY + e * 4;
    sA[e * SAS + u] = xr[0] * yr[1] + xr[1] * yr[2] + xr[2] * yr[3];
  }
  stageB(w1, 32, 0, sB0, t);
  stageB(w3, 32, 0, sB1, t);
  __syncthreads();
  float4 m1q[2];
  gemm2(sA, sB0, eh, eh + 32, cg, m1q[0], m1q[1]);
  __syncthreads();

  // ---- M0 build; o0 = M0 @ C0
#pragma unroll
  for (int ei = 0; ei < 2; ++ei) {
    int e = eh + 32 * ei;
    float y0v = sY[e * 4];
    *(float4*)(sA + e * SAS + 4 * cg)      = cmul(m0q[ei], wq[ei][0], pw * y0v);
    *(float4*)(sA + e * SAS + 32 + 4 * cg) = cmul(m1q[ei], wq[ei][1], pws3);
  }
  stageB(C0, 32, 0, sB0, t);
  __syncthreads();
  float4 o0q[2];
  gemm2(sA, sB0, eh, eh + 32, cg, o0q[0], o0q[1]);
  __syncthreads();

  // ---- k-loop: mid3k = s1k @ w3; M1k; o1k = M1k @ C1   (C1 -> sB0)
  stageB(C1, 32, 0, sB0, t);
  float o1v[2][12];
#pragma unroll
  for (int k = 0; k < 3; ++k) {
    // s1k tile (on k==0 this sync also covers the C1 staging)
#pragma unroll 2
    for (int r = 0; r < 16; ++r) {
      int i = r * TPB + t; int e = i >> 6; int u = i & 63;
      const float* xr = ((u < 32) ? x1a : x1b) + (e0 + e) * 128 + 32 + 3 * (u & 31);
      sA[e * SAS + u] = xr[k];
    }
    __syncthreads();
    float4 t3[2];
    gemm2(sA, sB1, eh, eh + 32, cg, t3[0], t3[1]);   // @ w3
    __syncthreads();
#pragma unroll
    for (int ei = 0; ei < 2; ++ei) {
      int e = eh + 32 * ei;
      float y0v = sY[e * 4];
      float y1k = sY[e * 4 + 1 + k];
      *(float4*)(sA + e * SAS + 4 * cg)      = cmul(p2q[ei], wq[ei][2], pw * y1k);
      *(float4*)(sA + e * SAS + 32 + 4 * cg) = cmul(t3[ei], wq[ei][3], pw * y0v);
    }
    __syncthreads();
    float4 r0, r1;
    gemm2(sA, sB0, eh, eh + 32, cg, r0, r1);         // @ C1
    o1v[0][0 + k] = r0.x; o1v[0][3 + k] = r0.y; o1v[0][6 + k] = r0.z; o1v[0][9 + k] = r0.w;
    o1v[1][0 + k] = r1.x; o1v[1][3 + k] = r1.y; o1v[1][6 + k] = r1.z; o1v[1][9 + k] = r1.w;
    __syncthreads();
  }

  // ---- single contiguous store pass: 4 float4 per (thread, event)
#pragma unroll
  for (int ei = 0; ei < 2; ++ei) {
    long eg = e0 + eh + 32 * ei;
    float* ob = out + eg * 128;
    *(float4*)(ob + 4 * cg) = o0q[ei];
    float* o1b = ob + 32 + 12 * cg;
    *(float4*)(o1b)     = make_float4(o1v[ei][0], o1v[ei][1], o1v[ei][2],  o1v[ei][3]);
    *(float4*)(o1b + 4) = make_float4(o1v[ei][4], o1v[ei][5], o1v[ei][6],  o1v[ei][7]);
    *(float4*)(o1b + 8) = make_float4(o1v[ei][8], o1v[ei][9], o1v[ei][10], o1v[ei][11]);
  }
}

// ---------------------------------------------------------------------------
extern "C" void kernel_launch(void* const* d_in, const int* in_sizes, int n_in,
                              void* d_out, int out_size, void* d_ws, size_t ws_size,
                              hipStream_t stream) {
  const float* x1a     = (const float*)d_in[0];
  const float* x1b     = (const float*)d_in[1];
  const float* x2      = (const float*)d_in[2];
  const float* scalars = (const float*)d_in[3];
  const float* w0      = (const float*)d_in[4];
  const float* w1      = (const float*)d_in[5];
  const float* w2      = (const float*)d_in[6];
  const float* w3      = (const float*)d_in[7];
  const float* Wl0     = (const float*)d_in[8];
  const float* Wl1     = (const float*)d_in[9];
  const float* Wm1     = (const float*)d_in[10];
  const float* Wm2     = (const float*)d_in[11];
  const float* Wm3     = (const float*)d_in[12];
  const float* Wf0     = (const float*)d_in[13];
  const float* Wf1     = (const float*)d_in[14];
  float* out = (float*)d_out;

  double* cst = (double*)d_ws;
  float* C0 = (float*)d_ws + 128;   // 512 B offset: keeps C0/C1 16B-aligned
  float* C1 = C0 + 64 * 32;

  const int E = in_sizes[0] / 128;  // 200000
  const int nblocks = E / ET;       // 3125

  zero_cst_kernel<<<1, 64, 0, stream>>>(cst);
  cst_accum_kernel<<<64, 256, 0, stream>>>(cst);
  prep_C_kernel<<<2, 256, 0, stream>>>(Wl0, Wf0, Wl1, Wf1, C0, C1);
  fused_tp<<<nblocks, TPB, 0, stream>>>(x1a, x1b, x2, scalars, w0, w1, w2, w3,
                                        Wm1, Wm2, Wm3, C0, C1, cst, out);
}